// Round 3
// baseline (394.885 us; speedup 1.0000x reference)
//
#include <hip/hip_runtime.h>
#include <hip/hip_bf16.h>

// Problem constants (fixed by reference)
#define B_ 16
#define L_ 24
#define N_ 256
#define E_ 4096
#define T_ (B_ * L_)   // 384 graphs

// All tensors are float32 (reference dtype). Output [B,L,N,64] f32 = 25.2 MB.
// X (LSTM h states, [T,N,64] f32) lives in d_out; k_graph overwrites in place.
// ws holds folded tables only (~140 KB).
constexpr int WP    = 0;                   // P = W1a@W2b  (64x64)
constexpr int WRQ   = WP + 4096;           // R+Q = W2a + W1b@W2b (64x64)
constexpr int WRM   = WRQ + 4096;          // R = W2a (64x64)
constexpr int WBIAS = WRM + 4096;          // biasv [256][64]
constexpr int WALPHA= WBIAS + 16384;       // alpha[256]
constexpr int WBETA = WALPHA + 256;        // beta[256]
constexpr int WDINV = WBETA + 256;         // 1/max(cnt,1) [256]
constexpr int WSEL  = WDINV + 256;         // cnt>0 ? 1 : 0 [256]
constexpr int WSW   = WSEL + 256;          // sw0[256], sw1[256]
constexpr int WCNTF = WSW + 512;           // cnt as float [256]
constexpr int WCOLP = WCNTF + 256;         // 257 ints (CSR col ptr)
constexpr int WROWS = WCOLP + 260;         // 4096 ints (row node per edge, grouped by col)

__device__ __forceinline__ float sigm(float x) { return 1.f / (1.f + __expf(-x)); }
__device__ __forceinline__ float tanh_(float x) { return 2.f / (1.f + __expf(-2.f * x)) - 1.f; }
__device__ __forceinline__ float bcast(float v, int lane) {
    return __int_as_float(__builtin_amdgcn_readlane(__float_as_int(v), lane));
}

// ---------------- K1a: graph structure + LSTM input collapse ----------------
__global__ __launch_bounds__(256) void k_prep_a(
    const int* __restrict__ conn, const float* __restrict__ cw,
    const float* __restrict__ Wih, const float* __restrict__ embW,
    const float* __restrict__ embB, const float* __restrict__ bih,
    const float* __restrict__ bhh, float* __restrict__ ws) {
    __shared__ int s_cnt[N_];
    __shared__ float s_sw0[N_], s_sw1[N_];
    __shared__ int s_pos[N_];
    int t = threadIdx.x;
    s_cnt[t] = 0; s_sw0[t] = 0.f; s_sw1[t] = 0.f;
    __syncthreads();
    for (int e = t; e < E_; e += 256) {
        int c = conn[E_ + e] & 255;
        atomicAdd(&s_cnt[c], 1);
        atomicAdd(&s_sw0[c], cw[2 * e]);
        atomicAdd(&s_sw1[c], cw[2 * e + 1]);
    }
    __syncthreads();
    // exclusive prefix sum over 256 (broadcast reads, one-shot kernel)
    int excl = 0;
    for (int u = 0; u < t; ++u) excl += s_cnt[u];
    int* colp = (int*)(ws + WCOLP);
    colp[t] = excl;
    if (t == 0) colp[N_] = E_;
    s_pos[t] = excl;
    int cnt = s_cnt[t];
    ws[WCNTF + t] = (float)cnt;
    ws[WDINV + t] = 1.f / (float)(cnt > 1 ? cnt : 1);
    ws[WSEL + t]  = cnt > 0 ? 1.f : 0.f;
    ws[WSW + t]        = s_sw0[t];
    ws[WSW + N_ + t]   = s_sw1[t];
    // LSTM input collapse: xg[g] = aqi*alpha[g] + beta[g]
    float a = 0.f, b = 0.f;
    for (int i = 0; i < 16; ++i) {
        float w = Wih[t * 16 + i];
        a += w * embW[i];
        b += w * embB[i];
    }
    ws[WALPHA + t] = a;
    ws[WBETA + t]  = b + bih[t] + bhh[t];
    __syncthreads();
    int* rows = (int*)(ws + WROWS);
    for (int e = t; e < E_; e += 256) {
        int c = conn[E_ + e] & 255;
        int p = atomicAdd(&s_pos[c], 1);
        rows[p] = conn[e] & 255;
    }
}

// ---------------- K1b: fused weight products + per-node bias ----------------
__global__ __launch_bounds__(64) void k_prep_b(
    const float* __restrict__ m1W, const float* __restrict__ m1b,
    const float* __restrict__ m2W, const float* __restrict__ m2b,
    float* __restrict__ ws) {
    int blk = blockIdx.x, j = threadIdx.x;
    if (blk < N_) {                 // biasv[v] = ((sw@W1c + cnt*b1)@W2b)*dinv + b2
        int v = blk;
        float sw0 = ws[WSW + v], sw1 = ws[WSW + N_ + v];
        float cf = ws[WCNTF + v], dinv = ws[WDINV + v];
        float acc = 0.f;
        for (int m = 0; m < 64; ++m) {
            float tm = sw0 * m1W[128 * 64 + m] + sw1 * m1W[129 * 64 + m]
                     + cf * m1b[m];
            acc += tm * m2W[(64 + m) * 64 + j];
        }
        ws[WBIAS + v * 64 + j] = acc * dinv + m2b[j];
    } else if (blk == N_) {         // P = W1a @ W2b
        for (int k = 0; k < 64; ++k) {
            float acc = 0.f;
            for (int m = 0; m < 64; ++m)
                acc += m1W[k * 64 + m] * m2W[(64 + m) * 64 + j];
            ws[WP + k * 64 + j] = acc;
        }
    } else if (blk == N_ + 1) {     // RQ = W2a + W1b @ W2b
        for (int k = 0; k < 64; ++k) {
            float acc = m2W[k * 64 + j];
            for (int m = 0; m < 64; ++m)
                acc += m1W[(64 + k) * 64 + m] * m2W[(64 + m) * 64 + j];
            ws[WRQ + k * 64 + j] = acc;
        }
    } else {                        // RM = W2a
        for (int k = 0; k < 64; ++k)
            ws[WRM + k * 64 + j] = m2W[k * 64 + j];
    }
}

// ---------------- K2: LSTM. wave = 2 sequences, lane = hidden dim -----------
// h states written as f32 directly into d_out (layout [B,L,N,64] == [T,N,64]).
__global__ __launch_bounds__(256, 2) void k_lstm(
    const float* __restrict__ aqi, const float* __restrict__ Whh,
    const float* __restrict__ ws, float* __restrict__ xout) {
    __shared__ float Wl[16384];   // Wl[hp*256 + j*4 + k] = W_hh[(k*64+j)*64+hp]
    int t = threadIdx.x;
    #pragma unroll
    for (int i = 0; i < 64; ++i) {
        int idx = t + i * 256;
        int hp = idx >> 8, rem = idx & 255;
        int j = rem >> 2, k = rem & 3;
        Wl[idx] = Whh[(k * 64 + j) * 64 + hp];
    }
    __syncthreads();
    int wave = t >> 6, lane = t & 63;
    int s0 = (blockIdx.x * 4 + wave) * 2;   // sequence = b*256 + n
    int bA = s0 >> 8, nA = s0 & 255;
    int bB = (s0 + 1) >> 8, nB = (s0 + 1) & 255;
    float a0 = ws[WALPHA + lane], a1 = ws[WALPHA + 64 + lane];
    float a2 = ws[WALPHA + 128 + lane], a3 = ws[WALPHA + 192 + lane];
    float e0 = ws[WBETA + lane], e1 = ws[WBETA + 64 + lane];
    float e2 = ws[WBETA + 128 + lane], e3 = ws[WBETA + 192 + lane];
    float hA = 0.f, cA = 0.f, hB = 0.f, cB = 0.f;
    for (int l = 0; l < L_; ++l) {
        float xA = aqi[(bA * L_ + l) * N_ + nA];
        float xB = aqi[(bB * L_ + l) * N_ + nB];
        float g0A = fmaf(xA, a0, e0), g1A = fmaf(xA, a1, e1);
        float g2A = fmaf(xA, a2, e2), g3A = fmaf(xA, a3, e3);
        float g0B = fmaf(xB, a0, e0), g1B = fmaf(xB, a1, e1);
        float g2B = fmaf(xB, a2, e2), g3B = fmaf(xB, a3, e3);
        if (l > 0) {
            #pragma unroll 8
            for (int hp = 0; hp < 64; ++hp) {
                float hvA = bcast(hA, hp);
                float hvB = bcast(hB, hp);
                const float4 w = *(const float4*)&Wl[hp * 256 + lane * 4];
                g0A = fmaf(hvA, w.x, g0A); g1A = fmaf(hvA, w.y, g1A);
                g2A = fmaf(hvA, w.z, g2A); g3A = fmaf(hvA, w.w, g3A);
                g0B = fmaf(hvB, w.x, g0B); g1B = fmaf(hvB, w.y, g1B);
                g2B = fmaf(hvB, w.z, g2B); g3B = fmaf(hvB, w.w, g3B);
            }
        }
        float iA = sigm(g0A), fA = sigm(g1A), GA = tanh_(g2A), oA = sigm(g3A);
        cA = fmaf(fA, cA, iA * GA); hA = oA * tanh_(cA);
        float iB = sigm(g0B), fB = sigm(g1B), GB = tanh_(g2B), oB = sigm(g3B);
        cB = fmaf(fB, cB, iB * GB); hB = oB * tanh_(cB);
        xout[((bA * L_ + l) * N_ + nA) * 64 + lane] = hA;
        xout[((bB * L_ + l) * N_ + nB) * 64 + lane] = hB;
    }
}

// ---------------- K4: per-graph GNN (fused XP, gather, epilogue) ------------
// Reads its own [N,64] f32 X tile from `out` (staged to bf16 LDS), then
// overwrites that tile in place with the final output (f32).
constexpr int XS = 66;  // LDS row stride in bf16 (33 words: v%32 bank spread)

__global__ __launch_bounds__(256, 2) void k_graph(
    const float* __restrict__ ws, float* __restrict__ out) {
    __shared__ __hip_bfloat16 Xl[N_ * XS];
    __shared__ __hip_bfloat16 XPl[N_ * XS];
    int tg = blockIdx.x;
    int tid = threadIdx.x;
    // stage this graph's X tile (16384 f32 = 4096 float4) into bf16 LDS
    const float4* src = (const float4*)(out + tg * (N_ * 64));
    #pragma unroll
    for (int it = 0; it < 16; ++it) {
        float4 d = src[tid + it * 256];
        int g0 = (tid + it * 256) * 4;        // f32 flat index
        int node = g0 >> 6, col = g0 & 63;    // col multiple of 4
        unsigned* dst = (unsigned*)&Xl[node * XS + col];  // 4B-aligned
        __hip_bfloat162 p0 = __halves2bfloat162(__float2bfloat16(d.x), __float2bfloat16(d.y));
        __hip_bfloat162 p1 = __halves2bfloat162(__float2bfloat16(d.z), __float2bfloat16(d.w));
        dst[0] = *(unsigned*)&p0;
        dst[1] = *(unsigned*)&p1;
    }
    __syncthreads();
    int v = tid;
    float acc[64];
    // phase 1: XP[v] = x[v] @ P
    #pragma unroll
    for (int j = 0; j < 64; ++j) acc[j] = 0.f;
    {
        const float* Pm = ws + WP;
        for (int k = 0; k < 64; ++k) {
            float xv = __bfloat162float(Xl[v * XS + k]);
            const float* Pr = Pm + k * 64;
            #pragma unroll
            for (int j = 0; j < 64; j += 4) {
                float4 p = *(const float4*)(Pr + j);
                acc[j]     = fmaf(xv, p.x, acc[j]);
                acc[j + 1] = fmaf(xv, p.y, acc[j + 1]);
                acc[j + 2] = fmaf(xv, p.z, acc[j + 2]);
                acc[j + 3] = fmaf(xv, p.w, acc[j + 3]);
            }
        }
        #pragma unroll
        for (int j = 0; j < 64; ++j) XPl[v * XS + j] = __float2bfloat16(acc[j]);
    }
    __syncthreads();
    // phase 2: out[v] = biasv + x@(R or R+Q) + dinv * sum_{in-edges} XP[row]
    float sel = ws[WSEL + v];
    float dinv = ws[WDINV + v];
    const float* Mb = (sel > 0.5f) ? (ws + WRQ) : (ws + WRM);
    const float* bv = ws + WBIAS + v * 64;
    #pragma unroll
    for (int j = 0; j < 64; ++j) acc[j] = bv[j];
    for (int k = 0; k < 64; ++k) {
        float xv = __bfloat162float(Xl[v * XS + k]);
        const float* Mr = Mb + k * 64;
        #pragma unroll
        for (int j = 0; j < 64; j += 4) {
            float4 m = *(const float4*)(Mr + j);
            acc[j]     = fmaf(xv, m.x, acc[j]);
            acc[j + 1] = fmaf(xv, m.y, acc[j + 1]);
            acc[j + 2] = fmaf(xv, m.z, acc[j + 2]);
            acc[j + 3] = fmaf(xv, m.w, acc[j + 3]);
        }
    }
    const int* colp = (const int*)(ws + WCOLP);
    const int* rows = (const int*)(ws + WROWS);
    int e1 = colp[v + 1];
    for (int e = colp[v]; e < e1; ++e) {
        int r = rows[e];
        const __hip_bfloat16* xp = &XPl[r * XS];
        #pragma unroll
        for (int j = 0; j < 64; j += 2) {
            unsigned u = *(const unsigned*)(xp + j);
            float f0 = __uint_as_float(u << 16);
            float f1 = __uint_as_float(u & 0xffff0000u);
            acc[j]     = fmaf(dinv, f0, acc[j]);
            acc[j + 1] = fmaf(dinv, f1, acc[j + 1]);
        }
    }
    float* og = out + (tg * N_ + v) * 64;
    #pragma unroll
    for (int j = 0; j < 64; j += 4) {
        float4 r4 = make_float4(acc[j], acc[j + 1], acc[j + 2], acc[j + 3]);
        *(float4*)(og + j) = r4;
    }
}

extern "C" void kernel_launch(void* const* d_in, const int* in_sizes, int n_in,
                              void* d_out, int out_size, void* d_ws, size_t ws_size,
                              hipStream_t stream) {
    const float* aqi  = (const float*)d_in[0];
    const int*   conn = (const int*)d_in[1];
    const float* cw   = (const float*)d_in[2];
    const float* embW = (const float*)d_in[3];
    const float* embB = (const float*)d_in[4];
    const float* Wih  = (const float*)d_in[5];
    const float* Whh  = (const float*)d_in[6];
    const float* bih  = (const float*)d_in[7];
    const float* bhh  = (const float*)d_in[8];
    const float* m1W  = (const float*)d_in[9];
    const float* m1b  = (const float*)d_in[10];
    const float* m2W  = (const float*)d_in[11];
    const float* m2b  = (const float*)d_in[12];
    float* ws  = (float*)d_ws;
    float* out = (float*)d_out;

    k_prep_a<<<dim3(1), dim3(256), 0, stream>>>(conn, cw, Wih, embW, embB, bih, bhh, ws);
    k_prep_b<<<dim3(N_ + 3), dim3(64), 0, stream>>>(m1W, m1b, m2W, m2b, ws);
    k_lstm<<<dim3(512), dim3(256), 0, stream>>>(aqi, Whh, ws, out);
    k_graph<<<dim3(T_), dim3(256), 0, stream>>>(ws, out);
}

// Round 5
// 306.781 us; speedup vs baseline: 1.2872x; 1.2872x over previous
//
#include <hip/hip_runtime.h>
#include <hip/hip_bf16.h>

// Problem constants (fixed by reference)
#define B_ 16
#define L_ 24
#define N_ 256
#define E_ 4096
#define T_ (B_ * L_)   // 384 graphs

// All tensors float32. Output [B,L,N,64] f32 = 25.2 MB.
// X (LSTM h states, [T,N,64] f32) lives in d_out; k_graph overwrites in place.
// ws holds folded tables only. RM dropped (k_graph reads m2W rows 0..63 directly).
constexpr int WP    = 0;                   // P = W1a@W2b  (64x64)
constexpr int WRQ   = WP + 4096;           // R+Q = W2a + W1b@W2b (64x64)
constexpr int WRM   = WRQ + 4096;          // (unused)
constexpr int WBIAS = WRM + 4096;          // biasv [256][64]
constexpr int WALPHA= WBIAS + 16384;       // alpha[256]
constexpr int WBETA = WALPHA + 256;        // beta[256]
constexpr int WDINV = WBETA + 256;         // 1/max(cnt,1) [256]
constexpr int WSEL  = WDINV + 256;         // cnt>0 ? 1 : 0 [256]
constexpr int WSW   = WSEL + 256;          // sw0[256], sw1[256]
constexpr int WCNTF = WSW + 512;           // cnt as float [256]
constexpr int WCOLP = WCNTF + 256;         // 257 ints (CSR col ptr)
constexpr int WROWS = WCOLP + 260;         // 4096 ints (row node per edge, grouped by col)

__device__ __forceinline__ float sigm(float x) { return 1.f / (1.f + __expf(-x)); }
__device__ __forceinline__ float tanh_(float x) { return 2.f / (1.f + __expf(-2.f * x)) - 1.f; }
__device__ __forceinline__ float bcast(float v, int lane) {
    return __int_as_float(__builtin_amdgcn_readlane(__float_as_int(v), lane));
}

// ------ K1a: graph structure + LSTM input collapse + U vectors + biasv ------
__global__ __launch_bounds__(256) void k_prep_a(
    const int* __restrict__ conn, const float* __restrict__ cw,
    const float* __restrict__ Wih, const float* __restrict__ embW,
    const float* __restrict__ embB, const float* __restrict__ bih,
    const float* __restrict__ bhh, const float* __restrict__ m1W,
    const float* __restrict__ m1b, const float* __restrict__ m2W,
    const float* __restrict__ m2b, float* __restrict__ ws) {
    __shared__ int s_cnt[N_];
    __shared__ float s_sw0[N_], s_sw1[N_];
    __shared__ int s_pos[N_];
    __shared__ float sU[3 * 64];
    int t = threadIdx.x;
    s_cnt[t] = 0; s_sw0[t] = 0.f; s_sw1[t] = 0.f;
    __syncthreads();
    for (int e = t; e < E_; e += 256) {
        int c = conn[E_ + e] & 255;
        atomicAdd(&s_cnt[c], 1);
        atomicAdd(&s_sw0[c], cw[2 * e]);
        atomicAdd(&s_sw1[c], cw[2 * e + 1]);
    }
    __syncthreads();
    // exclusive prefix sum over 256 (broadcast LDS reads, one-shot)
    int excl = 0;
    for (int u = 0; u < t; ++u) excl += s_cnt[u];
    int* colp = (int*)(ws + WCOLP);
    colp[t] = excl;
    if (t == 0) colp[N_] = E_;
    s_pos[t] = excl;
    int cnt = s_cnt[t];
    float cntf = (float)cnt;
    float dinv = 1.f / (float)(cnt > 1 ? cnt : 1);
    ws[WCNTF + t] = cntf;
    ws[WDINV + t] = dinv;
    ws[WSEL + t]  = cnt > 0 ? 1.f : 0.f;
    ws[WSW + t]        = s_sw0[t];
    ws[WSW + N_ + t]   = s_sw1[t];
    // LSTM input collapse: xg[g] = aqi*alpha[g] + beta[g]
    float a = 0.f, b = 0.f;
    for (int i = 0; i < 16; ++i) {
        float w = Wih[t * 16 + i];
        a += w * embW[i];
        b += w * embB[i];
    }
    ws[WALPHA + t] = a;
    ws[WBETA + t]  = b + bih[t] + bhh[t];
    __syncthreads();   // REQUIRED: all s_pos[] must be initialized before rows fill
    // CSR rows fill
    int* rows = (int*)(ws + WROWS);
    for (int e = t; e < E_; e += 256) {
        int c = conn[E_ + e] & 255;
        int p = atomicAdd(&s_pos[c], 1);
        rows[p] = conn[e] & 255;
    }
    // U vectors: U0 = W1c0@W2b, U1 = W1c1@W2b, U2 = b1@W2b   (3 x 64)
    if (t < 192) {
        int part = t >> 6, j = t & 63;
        float acc = 0.f;
        for (int m = 0; m < 64; ++m) {
            float w = (part == 0) ? m1W[128 * 64 + m]
                    : (part == 1) ? m1W[129 * 64 + m] : m1b[m];
            acc = fmaf(w, m2W[(64 + m) * 64 + j], acc);
        }
        sU[part * 64 + j] = acc;
    }
    __syncthreads();
    // biasv[v][j] = dinv_v*(sw0_v*U0[j] + sw1_v*U1[j] + cnt_v*U2[j]) + b2[j]
    for (int i = 0; i < 64; ++i) {
        int idx = t + (i << 8);
        int v = idx >> 6, j = idx & 63;
        int cv = s_cnt[v];
        float dv = 1.f / (float)(cv > 1 ? cv : 1);
        float bb = s_sw0[v] * sU[j] + s_sw1[v] * sU[64 + j] + (float)cv * sU[128 + j];
        ws[WBIAS + idx] = dv * bb + m2b[j];
    }
}

// ---------------- K1w: P = W1a@W2b, RQ = W2a + W1b@W2b (parallel) -----------
__global__ __launch_bounds__(256) void k_prep_w(
    const float* __restrict__ m1W, const float* __restrict__ m2W,
    float* __restrict__ ws) {
    __shared__ float sB[64 * 64];   // W2b = m2W rows 64..127
    int t = threadIdx.x, blk = blockIdx.x;
    bool isP = blk < 4;
    int kbase = (blk & 3) * 16;
    #pragma unroll
    for (int i = 0; i < 16; ++i) sB[t + 256 * i] = m2W[64 * 64 + t + 256 * i];
    __syncthreads();
    int j = t & 63, kl = t >> 6;
    #pragma unroll
    for (int r = 0; r < 4; ++r) {
        int k = kbase + kl * 4 + r;
        const float* arow = m1W + (isP ? k : (64 + k)) * 64;
        float acc = isP ? 0.f : m2W[k * 64 + j];   // RQ includes W2a
        #pragma unroll
        for (int m = 0; m < 64; m += 4) {
            float4 a4 = *(const float4*)(arow + m);
            acc = fmaf(a4.x, sB[m * 64 + j], acc);
            acc = fmaf(a4.y, sB[(m + 1) * 64 + j], acc);
            acc = fmaf(a4.z, sB[(m + 2) * 64 + j], acc);
            acc = fmaf(a4.w, sB[(m + 3) * 64 + j], acc);
        }
        ws[(isP ? WP : WRQ) + k * 64 + j] = acc;
    }
}

// ---------------- K2: LSTM. wave = 4 sequences, lane = hidden dim -----------
// h states written f32 directly into d_out (layout [B,L,N,64] == [T,N,64]).
__global__ __launch_bounds__(256, 2) void k_lstm(
    const float* __restrict__ aqi, const float* __restrict__ Whh,
    const float* __restrict__ ws, float* __restrict__ xout) {
    __shared__ float Wl[16384];   // Wl[hp*256 + j*4 + k] = W_hh[(k*64+j)*64+hp]
    int t = threadIdx.x;
    #pragma unroll
    for (int i = 0; i < 64; ++i) {
        int idx = t + i * 256;
        int hp = idx >> 8, rem = idx & 255;
        int j = rem >> 2, k = rem & 3;
        Wl[idx] = Whh[(k * 64 + j) * 64 + hp];
    }
    __syncthreads();
    int wave = t >> 6, lane = t & 63;
    int s0 = (blockIdx.x * 4 + wave) * 4;   // sequence = b*256 + n; n0 % 4 == 0
    int b0 = s0 >> 8, n0 = s0 & 255;
    float a0 = ws[WALPHA + lane], a1 = ws[WALPHA + 64 + lane];
    float a2 = ws[WALPHA + 128 + lane], a3 = ws[WALPHA + 192 + lane];
    float e0 = ws[WBETA + lane], e1 = ws[WBETA + 64 + lane];
    float e2 = ws[WBETA + 128 + lane], e3 = ws[WBETA + 192 + lane];
    float h[4] = {0.f, 0.f, 0.f, 0.f}, c[4] = {0.f, 0.f, 0.f, 0.f};
    for (int l = 0; l < L_; ++l) {
        const float* xr = aqi + (b0 * L_ + l) * N_ + n0;
        float g0[4], g1[4], g2[4], g3[4];
        #pragma unroll
        for (int s = 0; s < 4; ++s) {
            float x = xr[s];
            g0[s] = fmaf(x, a0, e0); g1[s] = fmaf(x, a1, e1);
            g2[s] = fmaf(x, a2, e2); g3[s] = fmaf(x, a3, e3);
        }
        if (l > 0) {
            #pragma unroll 8
            for (int hp = 0; hp < 64; ++hp) {
                const float4 w = *(const float4*)&Wl[hp * 256 + lane * 4];
                #pragma unroll
                for (int s = 0; s < 4; ++s) {
                    float hv = bcast(h[s], hp);
                    g0[s] = fmaf(hv, w.x, g0[s]); g1[s] = fmaf(hv, w.y, g1[s]);
                    g2[s] = fmaf(hv, w.z, g2[s]); g3[s] = fmaf(hv, w.w, g3[s]);
                }
            }
        }
        float* orow = xout + ((b0 * L_ + l) * N_ + n0) * 64 + lane;
        #pragma unroll
        for (int s = 0; s < 4; ++s) {
            float iv = sigm(g0[s]), fv = sigm(g1[s]);
            float gv = tanh_(g2[s]), ov = sigm(g3[s]);
            c[s] = fmaf(fv, c[s], iv * gv);
            h[s] = ov * tanh_(c[s]);
            orow[s * 64] = h[s];
        }
    }
}

// ---------------- K4: per-graph GNN (fused XP, gather, epilogue) ------------
// Reads its own [N,64] f32 X tile from `out` (staged to bf16 LDS), then
// overwrites that tile in place with the final output (f32).
constexpr int XS = 66;  // LDS row stride in bf16 (33 words: bank spread)

__global__ __launch_bounds__(256, 2) void k_graph(
    const float* __restrict__ ws, const float* __restrict__ m2W,
    float* __restrict__ out) {
    __shared__ __hip_bfloat16 Xl[N_ * XS];
    __shared__ __hip_bfloat16 XPl[N_ * XS];
    int tg = blockIdx.x;
    int tid = threadIdx.x;
    // stage this graph's X tile (16384 f32 = 4096 float4) into bf16 LDS
    const float4* src = (const float4*)(out + tg * (N_ * 64));
    #pragma unroll
    for (int it = 0; it < 16; ++it) {
        float4 d = src[tid + it * 256];
        int g0 = (tid + it * 256) * 4;        // f32 flat index
        int node = g0 >> 6, col = g0 & 63;    // col multiple of 4
        unsigned* dst = (unsigned*)&Xl[node * XS + col];  // 4B-aligned
        __hip_bfloat162 p0 = __halves2bfloat162(__float2bfloat16(d.x), __float2bfloat16(d.y));
        __hip_bfloat162 p1 = __halves2bfloat162(__float2bfloat16(d.z), __float2bfloat16(d.w));
        dst[0] = *(unsigned*)&p0;
        dst[1] = *(unsigned*)&p1;
    }
    __syncthreads();
    int v = tid;
    float acc[64];
    // phase 1: XP[v] = x[v] @ P
    #pragma unroll
    for (int j = 0; j < 64; ++j) acc[j] = 0.f;
    {
        const float* Pm = ws + WP;
        for (int k = 0; k < 64; ++k) {
            float xv = __bfloat162float(Xl[v * XS + k]);
            const float* Pr = Pm + k * 64;
            #pragma unroll
            for (int j = 0; j < 64; j += 4) {
                float4 p = *(const float4*)(Pr + j);
                acc[j]     = fmaf(xv, p.x, acc[j]);
                acc[j + 1] = fmaf(xv, p.y, acc[j + 1]);
                acc[j + 2] = fmaf(xv, p.z, acc[j + 2]);
                acc[j + 3] = fmaf(xv, p.w, acc[j + 3]);
            }
        }
        #pragma unroll
        for (int j = 0; j < 64; ++j) XPl[v * XS + j] = __float2bfloat16(acc[j]);
    }
    __syncthreads();
    // phase 2: out[v] = biasv + x@(W2a or W2a+Q) + dinv * sum_{in-edges} XP[row]
    float sel = ws[WSEL + v];
    float dinv = ws[WDINV + v];
    const float* Mb = (sel > 0.5f) ? (ws + WRQ) : m2W;  // m2W rows 0..63 = W2a
    const float* bv = ws + WBIAS + v * 64;
    #pragma unroll
    for (int j = 0; j < 64; ++j) acc[j] = bv[j];
    for (int k = 0; k < 64; ++k) {
        float xv = __bfloat162float(Xl[v * XS + k]);
        const float* Mr = Mb + k * 64;
        #pragma unroll
        for (int j = 0; j < 64; j += 4) {
            float4 m = *(const float4*)(Mr + j);
            acc[j]     = fmaf(xv, m.x, acc[j]);
            acc[j + 1] = fmaf(xv, m.y, acc[j + 1]);
            acc[j + 2] = fmaf(xv, m.z, acc[j + 2]);
            acc[j + 3] = fmaf(xv, m.w, acc[j + 3]);
        }
    }
    const int* colp = (const int*)(ws + WCOLP);
    const int* rows = (const int*)(ws + WROWS);
    int e1 = colp[v + 1];
    for (int e = colp[v]; e < e1; ++e) {
        int r = rows[e];
        const __hip_bfloat16* xp = &XPl[r * XS];
        #pragma unroll
        for (int j = 0; j < 64; j += 2) {
            unsigned u = *(const unsigned*)(xp + j);
            float f0 = __uint_as_float(u << 16);
            float f1 = __uint_as_float(u & 0xffff0000u);
            acc[j]     = fmaf(dinv, f0, acc[j]);
            acc[j + 1] = fmaf(dinv, f1, acc[j + 1]);
        }
    }
    float* og = out + (tg * N_ + v) * 64;
    #pragma unroll
    for (int j = 0; j < 64; j += 4) {
        float4 r4 = make_float4(acc[j], acc[j + 1], acc[j + 2], acc[j + 3]);
        *(float4*)(og + j) = r4;
    }
}

extern "C" void kernel_launch(void* const* d_in, const int* in_sizes, int n_in,
                              void* d_out, int out_size, void* d_ws, size_t ws_size,
                              hipStream_t stream) {
    const float* aqi  = (const float*)d_in[0];
    const int*   conn = (const int*)d_in[1];
    const float* cw   = (const float*)d_in[2];
    const float* embW = (const float*)d_in[3];
    const float* embB = (const float*)d_in[4];
    const float* Wih  = (const float*)d_in[5];
    const float* Whh  = (const float*)d_in[6];
    const float* bih  = (const float*)d_in[7];
    const float* bhh  = (const float*)d_in[8];
    const float* m1W  = (const float*)d_in[9];
    const float* m1b  = (const float*)d_in[10];
    const float* m2W  = (const float*)d_in[11];
    const float* m2b  = (const float*)d_in[12];
    float* ws  = (float*)d_ws;
    float* out = (float*)d_out;

    k_prep_a<<<dim3(1), dim3(256), 0, stream>>>(conn, cw, Wih, embW, embB, bih, bhh,
                                                m1W, m1b, m2W, m2b, ws);
    k_prep_w<<<dim3(8), dim3(256), 0, stream>>>(m1W, m2W, ws);
    k_lstm<<<dim3(256), dim3(256), 0, stream>>>(aqi, Whh, ws, out);
    k_graph<<<dim3(T_), dim3(256), 0, stream>>>(ws, m2W, out);
}